// Round 11
// baseline (629.305 us; speedup 1.0000x reference)
//
#include <hip/hip_runtime.h>
#include <stdint.h>

// HeadwiseLowRankModule: out = blockdiag-GEMM(GEMM(hidden, VT^T), U^T), f32 I/O.
// ROUND 11: r9/r10 proven baseline + T3 "minimum 2-phase" pipeline:
// double-buffered LDS, next-tile global_load_lds issued BEFORE current-tile
// compute, ONE __syncthreads per K-tile (its implicit vmcnt(0) drain is now
// hidden under the MFMA phase). No raw barriers, no counted vmcnt, same
// register footprint as the proven kernel (~80 VGPR). XCD swizzle kept (free).

typedef short  bf16x8  __attribute__((ext_vector_type(8)));
typedef float  f32x4   __attribute__((ext_vector_type(4)));
typedef ushort ushort8 __attribute__((ext_vector_type(8)));
typedef float  flt4    __attribute__((ext_vector_type(4)));

__device__ __forceinline__ void gload_lds16(const ushort* g, ushort* l) {
    __builtin_amdgcn_global_load_lds(
        (const __attribute__((address_space(1))) uint32_t*)g,
        (__attribute__((address_space(3))) uint32_t*)l, 16, 0, 0);
}

__device__ __forceinline__ ushort f2bf(float f) {
    union { float f; uint32_t u; } c; c.f = f;
    uint32_t u = c.u;
    uint32_t r = (u + 0x7FFFu + ((u >> 16) & 1u)) >> 16;  // RNE
    return (ushort)r;
}

// ---- fused f32 -> bf16 conversion for all three inputs (one launch) ----
__device__ __forceinline__ void conv_seg(const float* __restrict__ in,
                                         ushort* __restrict__ out,
                                         long n8, int bid, int nblk) {
    const long stride = (long)nblk * 256;
    for (long i = (long)bid * 256 + threadIdx.x; i < n8; i += stride) {
        flt4 a = ((const flt4*)in)[2 * i];
        flt4 b = ((const flt4*)in)[2 * i + 1];
        ushort8 o;
        o[0] = f2bf(a[0]); o[1] = f2bf(a[1]); o[2] = f2bf(a[2]); o[3] = f2bf(a[3]);
        o[4] = f2bf(b[0]); o[5] = f2bf(b[1]); o[6] = f2bf(b[2]); o[7] = f2bf(b[3]);
        ((ushort8*)out)[i] = o;
    }
}

__global__ __launch_bounds__(256) void convert_all_kernel(
    const float* __restrict__ hid_f, ushort* __restrict__ hid_b, long nHid8,
    const float* __restrict__ vt_f,  ushort* __restrict__ vt_b,  long nVT8,
    const float* __restrict__ u_f,   ushort* __restrict__ u_b,   long nU8)
{
    const int b = blockIdx.x;
    if (b < 1792)      conv_seg(hid_f, hid_b, nHid8, b,        1792);
    else if (b < 2016) conv_seg(vt_f,  vt_b,  nVT8,  b - 1792, 224);
    else               conv_seg(u_f,   u_b,   nU8,   b - 2016, 32);
}

// ---- store helpers (bf16 or f32 output) ----
__device__ __forceinline__ void store_out(ushort* p, float v) { *p = f2bf(v); }
__device__ __forceinline__ void store_out(float*  p, float v) { *p = v; }

// C[M x ldc] = A[. x lda] * B[. x ldb]^T  (A,B bf16 row-major, K contiguous)
// 128x128 tile, BK=64, 4 waves (2x2 of 64x64), DOUBLE-BUFFERED LDS,
// single __syncthreads per K-tile with prefetch issued before compute.
template <typename TOUT>
__global__ __launch_bounds__(256) void gemm_bt_kernel(
    const ushort* __restrict__ A,
    const ushort* __restrict__ B,
    TOUT* __restrict__ C,
    int lda, int ldb, int ldc, int K, int bxShift,
    long aOffZ, long bOffZ, long cOffZ)
{
    A += (size_t)blockIdx.z * aOffZ;
    B += (size_t)blockIdx.z * bOffZ;
    C += (size_t)blockIdx.z * cOffZ;

    __shared__ ushort As[2][128 * 64];   // 2 x 16 KiB
    __shared__ ushort Bs[2][128 * 64];   // 2 x 16 KiB

    const int tid  = threadIdx.x;
    const int lane = tid & 63;
    const int wave = tid >> 6;

    // XCD-aware swizzle: XCD k owns a contiguous M-stripe (bijective)
    const int bid = blockIdx.x;
    const int xcd = bid & 7;
    const int rr  = bid >> 3;
    const int by  = xcd * 16 + (rr >> bxShift);
    const int bx  = rr & ((1 << bxShift) - 1);

    const int row0 = by * 128;
    const int col0 = bx * 128;

    const int wr = wave >> 1;
    const int wc = wave & 1;

    const int l15    = lane & 15;
    const int lq     = lane >> 4;    // 0..3
    const int lrow   = lane >> 3;    // 0..7 (staging row in 8-row segment)
    const int lchunk = lane & 7;     // 0..7 (16B chunk within row)

    f32x4 acc[4][4] = {};

    const ushort* aPtr = A + (size_t)(row0 + wave * 32 + lrow) * lda + lchunk * 8;
    const ushort* bPtr = B + (size_t)(col0 + wave * 32 + lrow) * ldb + lchunk * 8;

    const int nkt = K / 64;

    // prologue: stage tile 0 into buffer 0, wait for it
    #pragma unroll
    for (int i = 0; i < 4; ++i) {
        gload_lds16(aPtr + (size_t)i * 8 * lda, As[0] + (wave * 4 + i) * 512);
        gload_lds16(bPtr + (size_t)i * 8 * ldb, Bs[0] + (wave * 4 + i) * 512);
    }
    __syncthreads();   // implicit vmcnt(0): tile 0 resident

    for (int kt = 0; kt < nkt; ++kt) {
        const int cur = kt & 1;

        // issue next-tile staging FIRST (flies during compute below)
        if (kt + 1 < nkt) {
            const int kOff = (kt + 1) * 64;
            #pragma unroll
            for (int i = 0; i < 4; ++i) {
                gload_lds16(aPtr + (size_t)i * 8 * lda + kOff,
                            As[cur ^ 1] + (wave * 4 + i) * 512);
                gload_lds16(bPtr + (size_t)i * 8 * ldb + kOff,
                            Bs[cur ^ 1] + (wave * 4 + i) * 512);
            }
        }

        // compute current tile
        #pragma unroll
        for (int kk = 0; kk < 2; ++kk) {
            bf16x8 af[4], bfr[4];
            #pragma unroll
            for (int m = 0; m < 4; ++m)
                af[m] = *(const bf16x8*)&As[cur][(wr * 64 + m * 16 + l15) * 64 + kk * 32 + lq * 8];
            #pragma unroll
            for (int n = 0; n < 4; ++n)
                bfr[n] = *(const bf16x8*)&Bs[cur][(wc * 64 + n * 16 + l15) * 64 + kk * 32 + lq * 8];
            #pragma unroll
            for (int m = 0; m < 4; ++m)
                #pragma unroll
                for (int n = 0; n < 4; ++n)
                    acc[m][n] = __builtin_amdgcn_mfma_f32_16x16x32_bf16(
                        af[m], bfr[n], acc[m][n], 0, 0, 0);
        }

        // one barrier per tile: drains staging (vmcnt 0) + syncs reads of cur
        __syncthreads();
    }

    // C/D layout: col = lane&15, row = (lane>>4)*4 + reg  [m89/m91 verified]
    #pragma unroll
    for (int m = 0; m < 4; ++m) {
        #pragma unroll
        for (int r = 0; r < 4; ++r) {
            const size_t row = (size_t)(row0 + wr * 64 + m * 16 + lq * 4 + r);
            TOUT* cRow = C + row * ldc + col0 + wc * 64 + l15;
            #pragma unroll
            for (int n = 0; n < 4; ++n)
                store_out(cRow + n * 16, acc[m][n][r]);
        }
    }
}

extern "C" void kernel_launch(void* const* d_in, const int* in_sizes, int n_in,
                              void* d_out, int out_size, void* d_ws, size_t ws_size,
                              hipStream_t stream) {
    const float* hidden_f = (const float*)d_in[0];  // 16384 x 4096 f32
    const float* VT_f     = (const float*)d_in[1];  // 2048 x 4096 f32 (N,K)
    const float* U_f      = (const float*)d_in[2];  // 8 x 512 x 256 f32
    float* out = (float*)d_out;                     // 16384 x 4096 f32

    const long nHid = 16384L * 4096L;
    const long nVT  = 2048L * 4096L;
    const long nU   = 8L * 512L * 256L;
    const long nLat = 16384L * 2048L;

    ushort *hid_b, *vt_b, *u_b, *lat_b;
    const size_t needA = (size_t)(nHid + nVT + nU + nLat) * 2;
    if (ws_size >= needA) {
        ushort* w = (ushort*)d_ws;
        hid_b = w;  vt_b = hid_b + nHid;  u_b = vt_b + nVT;  lat_b = u_b + nU;
    } else {
        ushort* w = (ushort*)d_ws;
        lat_b = w;  u_b = lat_b + nLat;
        ushort* o = (ushort*)d_out;       // staged in d_out; fully overwritten by GEMM2
        hid_b = o;  vt_b = hid_b + nHid;
    }

    // fused input conversion (one launch)
    convert_all_kernel<<<dim3(2048), dim3(256), 0, stream>>>(
        hidden_f, hid_b, nHid / 8,
        VT_f,     vt_b,  nVT / 8,
        U_f,      u_b,   nU / 8);

    // GEMM1: latent[16384 x 2048] = hid * VT^T
    // flat grid 2048 = 8 xcd * 16 stripe-rows * 16 col tiles (bxShift=4)
    gemm_bt_kernel<ushort><<<dim3(2048, 1, 1), dim3(256), 0, stream>>>(
        hid_b, vt_b, lat_b, 4096, 4096, 2048, 4096, 4,
        0L, 0L, 0L);

    // GEMM2 (block-diag): out[:, g*512:+512] = latent[:, g*256:+256] * U[g]^T
    // per-z flat grid 512 = 8 xcd * 16 stripe-rows * 4 col tiles (bxShift=2)
    gemm_bt_kernel<float><<<dim3(512, 1, 8), dim3(256), 0, stream>>>(
        lat_b, u_b, out, 2048, 256, 4096, 256, 2,
        256L, 512L * 256L, 512L);
}

// Round 12
// 572.617 us; speedup vs baseline: 1.0990x; 1.0990x over previous
//
#include <hip/hip_runtime.h>
#include <stdint.h>

// HeadwiseLowRankModule: out = blockdiag-GEMM(GEMM(hidden, VT^T), U^T), f32 I/O.
// ROUND 12: r11 dbuf REVERTED (occupancy loss, -23%). Back to single-buffer
// 2-barrier structure, but re-partitioned: SAME 128x128 tile over 8 WAVES
// (512-thread block, 64x32 per-wave sub-tile, acc 32 regs/thread).
// LDS stays 32 KiB -> 3-4 blocks/CU x 8 waves = 24-32 waves/CU (vs 20).
// Mechanism: inter-block/wave TLP is what hides staging latency (r11 lesson).

typedef short  bf16x8  __attribute__((ext_vector_type(8)));
typedef float  f32x4   __attribute__((ext_vector_type(4)));
typedef ushort ushort8 __attribute__((ext_vector_type(8)));
typedef float  flt4    __attribute__((ext_vector_type(4)));

__device__ __forceinline__ void gload_lds16(const ushort* g, ushort* l) {
    __builtin_amdgcn_global_load_lds(
        (const __attribute__((address_space(1))) uint32_t*)g,
        (__attribute__((address_space(3))) uint32_t*)l, 16, 0, 0);
}

__device__ __forceinline__ ushort f2bf(float f) {
    union { float f; uint32_t u; } c; c.f = f;
    uint32_t u = c.u;
    uint32_t r = (u + 0x7FFFu + ((u >> 16) & 1u)) >> 16;  // RNE
    return (ushort)r;
}

// ---- fused f32 -> bf16 conversion for all three inputs (one launch) ----
__device__ __forceinline__ void conv_seg(const float* __restrict__ in,
                                         ushort* __restrict__ out,
                                         long n8, int bid, int nblk) {
    const long stride = (long)nblk * 256;
    for (long i = (long)bid * 256 + threadIdx.x; i < n8; i += stride) {
        flt4 a = ((const flt4*)in)[2 * i];
        flt4 b = ((const flt4*)in)[2 * i + 1];
        ushort8 o;
        o[0] = f2bf(a[0]); o[1] = f2bf(a[1]); o[2] = f2bf(a[2]); o[3] = f2bf(a[3]);
        o[4] = f2bf(b[0]); o[5] = f2bf(b[1]); o[6] = f2bf(b[2]); o[7] = f2bf(b[3]);
        ((ushort8*)out)[i] = o;
    }
}

__global__ __launch_bounds__(256) void convert_all_kernel(
    const float* __restrict__ hid_f, ushort* __restrict__ hid_b, long nHid8,
    const float* __restrict__ vt_f,  ushort* __restrict__ vt_b,  long nVT8,
    const float* __restrict__ u_f,   ushort* __restrict__ u_b,   long nU8)
{
    const int b = blockIdx.x;
    if (b < 1792)      conv_seg(hid_f, hid_b, nHid8, b,        1792);
    else if (b < 2016) conv_seg(vt_f,  vt_b,  nVT8,  b - 1792, 224);
    else               conv_seg(u_f,   u_b,   nU8,   b - 2016, 32);
}

// ---- store helpers (bf16 or f32 output) ----
__device__ __forceinline__ void store_out(ushort* p, float v) { *p = f2bf(v); }
__device__ __forceinline__ void store_out(float*  p, float v) { *p = v; }

// C[M x ldc] = A[. x lda] * B[. x ldb]^T  (A,B bf16 row-major, K contiguous)
// 128x128 tile, BK=64, 8 waves (2x4 grid of 64x32 sub-tiles), single-buffer,
// 2 barriers per K-tile (the r2/r9 proven schedule, re-partitioned).
template <typename TOUT>
__global__ __launch_bounds__(512) void gemm_bt_kernel(
    const ushort* __restrict__ A,
    const ushort* __restrict__ B,
    TOUT* __restrict__ C,
    int lda, int ldb, int ldc, int K, int bxShift,
    long aOffZ, long bOffZ, long cOffZ)
{
    A += (size_t)blockIdx.z * aOffZ;
    B += (size_t)blockIdx.z * bOffZ;
    C += (size_t)blockIdx.z * cOffZ;

    __shared__ ushort As[128 * 64];   // 16 KiB
    __shared__ ushort Bs[128 * 64];   // 16 KiB

    const int tid  = threadIdx.x;
    const int lane = tid & 63;
    const int wave = tid >> 6;       // 0..7

    // XCD-aware swizzle: XCD k owns a contiguous M-stripe (bijective)
    const int bid = blockIdx.x;
    const int xcd = bid & 7;
    const int rr  = bid >> 3;
    const int by  = xcd * 16 + (rr >> bxShift);
    const int bx  = rr & ((1 << bxShift) - 1);

    const int row0 = by * 128;
    const int col0 = bx * 128;

    const int wr = wave >> 2;        // 0..1 (64-row half)
    const int wc = wave & 3;         // 0..3 (32-col quarter)

    const int l15    = lane & 15;
    const int lq     = lane >> 4;    // 0..3
    const int lrow   = lane >> 3;    // 0..7 (staging row in 8-row segment)
    const int lchunk = lane & 7;     // 0..7 (16B chunk within row)

    f32x4 acc[4][2] = {};            // 32 regs/thread

    // staging: wave w covers rows [w*8, w*8+8) of each 64-row half
    const ushort* aPtr = A + (size_t)(row0 + wave * 8 + lrow) * lda + lchunk * 8;
    const ushort* bPtr = B + (size_t)(col0 + wave * 8 + lrow) * ldb + lchunk * 8;
    // LDS dest (wave-uniform base, lane*16B implicit): half i -> i*4096 + wave*512
    const int ldsseg = wave * 512;

    const int nkt = K / 64;
    for (int kt = 0; kt < nkt; ++kt) {
        const int kOff = kt * 64;
        __syncthreads();
        #pragma unroll
        for (int i = 0; i < 2; ++i) {
            gload_lds16(aPtr + (size_t)i * 64 * lda + kOff, As + i * 4096 + ldsseg);
            gload_lds16(bPtr + (size_t)i * 64 * ldb + kOff, Bs + i * 4096 + ldsseg);
        }
        __syncthreads();

        #pragma unroll
        for (int kk = 0; kk < 2; ++kk) {
            bf16x8 af[4], bfr[2];
            #pragma unroll
            for (int m = 0; m < 4; ++m)
                af[m] = *(const bf16x8*)&As[(wr * 64 + m * 16 + l15) * 64 + kk * 32 + lq * 8];
            #pragma unroll
            for (int n = 0; n < 2; ++n)
                bfr[n] = *(const bf16x8*)&Bs[(wc * 32 + n * 16 + l15) * 64 + kk * 32 + lq * 8];
            #pragma unroll
            for (int m = 0; m < 4; ++m)
                #pragma unroll
                for (int n = 0; n < 2; ++n)
                    acc[m][n] = __builtin_amdgcn_mfma_f32_16x16x32_bf16(
                        af[m], bfr[n], acc[m][n], 0, 0, 0);
        }
    }

    // C/D layout: col = lane&15, row = (lane>>4)*4 + reg  [m89/m91 verified]
    #pragma unroll
    for (int m = 0; m < 4; ++m) {
        #pragma unroll
        for (int r = 0; r < 4; ++r) {
            const size_t row = (size_t)(row0 + wr * 64 + m * 16 + lq * 4 + r);
            TOUT* cRow = C + row * ldc + col0 + wc * 32 + l15;
            #pragma unroll
            for (int n = 0; n < 2; ++n)
                store_out(cRow + n * 16, acc[m][n][r]);
        }
    }
}

extern "C" void kernel_launch(void* const* d_in, const int* in_sizes, int n_in,
                              void* d_out, int out_size, void* d_ws, size_t ws_size,
                              hipStream_t stream) {
    const float* hidden_f = (const float*)d_in[0];  // 16384 x 4096 f32
    const float* VT_f     = (const float*)d_in[1];  // 2048 x 4096 f32 (N,K)
    const float* U_f      = (const float*)d_in[2];  // 8 x 512 x 256 f32
    float* out = (float*)d_out;                     // 16384 x 4096 f32

    const long nHid = 16384L * 4096L;
    const long nVT  = 2048L * 4096L;
    const long nU   = 8L * 512L * 256L;
    const long nLat = 16384L * 2048L;

    ushort *hid_b, *vt_b, *u_b, *lat_b;
    const size_t needA = (size_t)(nHid + nVT + nU + nLat) * 2;
    if (ws_size >= needA) {
        ushort* w = (ushort*)d_ws;
        hid_b = w;  vt_b = hid_b + nHid;  u_b = vt_b + nVT;  lat_b = u_b + nU;
    } else {
        ushort* w = (ushort*)d_ws;
        lat_b = w;  u_b = lat_b + nLat;
        ushort* o = (ushort*)d_out;       // staged in d_out; fully overwritten by GEMM2
        hid_b = o;  vt_b = hid_b + nHid;
    }

    // fused input conversion (one launch)
    convert_all_kernel<<<dim3(2048), dim3(256), 0, stream>>>(
        hidden_f, hid_b, nHid / 8,
        VT_f,     vt_b,  nVT / 8,
        U_f,      u_b,   nU / 8);

    // GEMM1: latent[16384 x 2048] = hid * VT^T
    // flat grid 2048 = 8 xcd * 16 stripe-rows * 16 col tiles (bxShift=4)
    gemm_bt_kernel<ushort><<<dim3(2048, 1, 1), dim3(512), 0, stream>>>(
        hid_b, vt_b, lat_b, 4096, 4096, 2048, 4096, 4,
        0L, 0L, 0L);

    // GEMM2 (block-diag): out[:, g*512:+512] = latent[:, g*256:+256] * U[g]^T
    // per-z flat grid 512 = 8 xcd * 16 stripe-rows * 4 col tiles (bxShift=2)
    gemm_bt_kernel<float><<<dim3(512, 1, 8), dim3(512), 0, stream>>>(
        lat_b, u_b, out, 2048, 256, 4096, 256, 2,
        256L, 512L * 256L, 512L);
}

// Round 13
// 533.298 us; speedup vs baseline: 1.1800x; 1.0737x over previous
//
#include <hip/hip_runtime.h>
#include <stdint.h>

// HeadwiseLowRankModule: out = blockdiag-GEMM(GEMM(hidden, VT^T), U^T), f32 I/O.
// ROUND 13: recombination of measured winners + hidden-convert fusion.
//  - GEMM1: r9 4-wave 128x128 body (best measured, 373us), A-side now reads
//    hidden F32 directly: reg-stage 8 f32 -> v_cvt_pk_bf16_f32 x4 ->
//    ds_write_b128 into the IDENTICAL linear LDS slot. B/MFMA/epilogue same.
//  - GEMM2: r12 8-wave 512-thread kernel verbatim (~70us vs ~100us at 4-wave;
//    short-K + f32-write-heavy benefits from 81% occupancy).
//  - convert kernel: VT + U only (~15us; hidden pass eliminated).

typedef short  bf16x8  __attribute__((ext_vector_type(8)));
typedef float  f32x4   __attribute__((ext_vector_type(4)));
typedef ushort ushort8 __attribute__((ext_vector_type(8)));
typedef float  flt4    __attribute__((ext_vector_type(4)));

__device__ __forceinline__ void gload_lds16(const ushort* g, ushort* l) {
    __builtin_amdgcn_global_load_lds(
        (const __attribute__((address_space(1))) uint32_t*)g,
        (__attribute__((address_space(3))) uint32_t*)l, 16, 0, 0);
}

__device__ __forceinline__ ushort f2bf(float f) {
    union { float f; uint32_t u; } c; c.f = f;
    uint32_t u = c.u;
    uint32_t r = (u + 0x7FFFu + ((u >> 16) & 1u)) >> 16;  // RNE
    return (ushort)r;
}

// packed f32x2 -> bf16x2 (1 inst; scalar f2bf would be ~4 VALU/elem)
__device__ __forceinline__ uint32_t cvtpk(float lo, float hi) {
    uint32_t r;
    asm("v_cvt_pk_bf16_f32 %0, %1, %2" : "=v"(r) : "v"(lo), "v"(hi));
    return r;
}

// ---- f32 -> bf16 conversion for VT + U only ----
__device__ __forceinline__ void conv_seg(const float* __restrict__ in,
                                         ushort* __restrict__ out,
                                         long n8, int bid, int nblk) {
    const long stride = (long)nblk * 256;
    for (long i = (long)bid * 256 + threadIdx.x; i < n8; i += stride) {
        flt4 a = ((const flt4*)in)[2 * i];
        flt4 b = ((const flt4*)in)[2 * i + 1];
        ushort8 o;
        o[0] = f2bf(a[0]); o[1] = f2bf(a[1]); o[2] = f2bf(a[2]); o[3] = f2bf(a[3]);
        o[4] = f2bf(b[0]); o[5] = f2bf(b[1]); o[6] = f2bf(b[2]); o[7] = f2bf(b[3]);
        ((ushort8*)out)[i] = o;
    }
}

__global__ __launch_bounds__(256) void convert_vt_u_kernel(
    const float* __restrict__ vt_f, ushort* __restrict__ vt_b, long nVT8,
    const float* __restrict__ u_f,  ushort* __restrict__ u_b,  long nU8)
{
    const int b = blockIdx.x;
    if (b < 896) conv_seg(vt_f, vt_b, nVT8, b,       896);
    else         conv_seg(u_f,  u_b,  nU8,  b - 896, 128);
}

// ---- store helpers ----
__device__ __forceinline__ void store_out(ushort* p, float v) { *p = f2bf(v); }
__device__ __forceinline__ void store_out(float*  p, float v) { *p = v; }

// =====================================================================
// GEMM1: latent[16384 x 2048] = hidden_f32[16384 x 4096] * VT_bf16^T
// r9 proven 4-wave 128x128 body; A staged from f32 via cvt_pk + ds_write
// into the identical linear LDS layout. B via global_load_lds (unchanged).
// =====================================================================
__global__ __launch_bounds__(256) void gemm1_fused_kernel(
    const float* __restrict__ Af,
    const ushort* __restrict__ B,
    ushort* __restrict__ C,
    int lda, int ldb, int ldc, int K, int bxShift)
{
    __shared__ ushort As[128 * 64];   // 16 KiB
    __shared__ ushort Bs[128 * 64];   // 16 KiB

    const int tid  = threadIdx.x;
    const int lane = tid & 63;
    const int wave = tid >> 6;

    // XCD-aware swizzle (bijective; grid = 8*16*2^bxShift)
    const int bid = blockIdx.x;
    const int xcd = bid & 7;
    const int rr  = bid >> 3;
    const int by  = xcd * 16 + (rr >> bxShift);
    const int bx  = rr & ((1 << bxShift) - 1);

    const int row0 = by * 128;
    const int col0 = bx * 128;

    const int wr = wave >> 1;
    const int wc = wave & 1;

    const int l15    = lane & 15;
    const int lq     = lane >> 4;    // 0..3
    const int lrow   = lane >> 3;    // 0..7
    const int lchunk = lane & 7;     // 0..7

    f32x4 acc[4][4] = {};

    const float*  aF   = Af + (size_t)(row0 + wave * 32 + lrow) * lda + lchunk * 8;
    const ushort* bPtr = B  + (size_t)(col0 + wave * 32 + lrow) * ldb + lchunk * 8;
    ushort* aDstBase = As + wave * 4 * 512 + lane * 8;  // per-thread LDS slot

    const int nkt = K / 64;
    for (int kt = 0; kt < nkt; ++kt) {
        const int kOff = kt * 64;
        __syncthreads();
        // B: async global->LDS (4 x 16B)
        #pragma unroll
        for (int i = 0; i < 4; ++i)
            gload_lds16(bPtr + (size_t)i * 8 * ldb + kOff, Bs + (wave * 4 + i) * 512);
        // A: f32 reg-stage -> cvt_pk -> ds_write_b128 (identical LDS layout)
        #pragma unroll
        for (int i = 0; i < 4; ++i) {
            const float* src = aF + (size_t)(i * 8) * lda + kOff;
            flt4 lo = *(const flt4*)(src);
            flt4 hi = *(const flt4*)(src + 4);
            uint4 w;
            w.x = cvtpk(lo[0], lo[1]);
            w.y = cvtpk(lo[2], lo[3]);
            w.z = cvtpk(hi[0], hi[1]);
            w.w = cvtpk(hi[2], hi[3]);
            *(uint4*)(aDstBase + i * 512) = w;
        }
        __syncthreads();   // drains gload_lds (vmcnt) + ds_writes (lgkm)

        #pragma unroll
        for (int kk = 0; kk < 2; ++kk) {
            bf16x8 af[4], bfr[4];
            #pragma unroll
            for (int m = 0; m < 4; ++m)
                af[m] = *(const bf16x8*)&As[(wr * 64 + m * 16 + l15) * 64 + kk * 32 + lq * 8];
            #pragma unroll
            for (int n = 0; n < 4; ++n)
                bfr[n] = *(const bf16x8*)&Bs[(wc * 64 + n * 16 + l15) * 64 + kk * 32 + lq * 8];
            #pragma unroll
            for (int m = 0; m < 4; ++m)
                #pragma unroll
                for (int n = 0; n < 4; ++n)
                    acc[m][n] = __builtin_amdgcn_mfma_f32_16x16x32_bf16(
                        af[m], bfr[n], acc[m][n], 0, 0, 0);
        }
    }

    // C/D layout: col = lane&15, row = (lane>>4)*4 + reg
    #pragma unroll
    for (int m = 0; m < 4; ++m) {
        #pragma unroll
        for (int r = 0; r < 4; ++r) {
            const size_t row = (size_t)(row0 + wr * 64 + m * 16 + lq * 4 + r);
            ushort* cRow = C + row * ldc + col0 + wc * 64 + l15;
            #pragma unroll
            for (int n = 0; n < 4; ++n)
                cRow[n * 16] = f2bf(acc[m][n][r]);
        }
    }
}

// =====================================================================
// GEMM2 (r12 8-wave verbatim, passed refcheck): block-diagonal
// out[:, g*512:+512] = latent[:, g*256:+256] * U[g]^T, f32 out.
// =====================================================================
template <typename TOUT>
__global__ __launch_bounds__(512) void gemm_bt8_kernel(
    const ushort* __restrict__ A,
    const ushort* __restrict__ B,
    TOUT* __restrict__ C,
    int lda, int ldb, int ldc, int K, int bxShift,
    long aOffZ, long bOffZ, long cOffZ)
{
    A += (size_t)blockIdx.z * aOffZ;
    B += (size_t)blockIdx.z * bOffZ;
    C += (size_t)blockIdx.z * cOffZ;

    __shared__ ushort As[128 * 64];
    __shared__ ushort Bs[128 * 64];

    const int tid  = threadIdx.x;
    const int lane = tid & 63;
    const int wave = tid >> 6;       // 0..7

    const int bid = blockIdx.x;
    const int xcd = bid & 7;
    const int rr  = bid >> 3;
    const int by  = xcd * 16 + (rr >> bxShift);
    const int bx  = rr & ((1 << bxShift) - 1);

    const int row0 = by * 128;
    const int col0 = bx * 128;

    const int wr = wave >> 2;        // 0..1
    const int wc = wave & 3;         // 0..3

    const int l15    = lane & 15;
    const int lq     = lane >> 4;
    const int lrow   = lane >> 3;
    const int lchunk = lane & 7;

    f32x4 acc[4][2] = {};

    const ushort* aPtr = A + (size_t)(row0 + wave * 8 + lrow) * lda + lchunk * 8;
    const ushort* bPtr = B + (size_t)(col0 + wave * 8 + lrow) * ldb + lchunk * 8;
    const int ldsseg = wave * 512;

    const int nkt = K / 64;
    for (int kt = 0; kt < nkt; ++kt) {
        const int kOff = kt * 64;
        __syncthreads();
        #pragma unroll
        for (int i = 0; i < 2; ++i) {
            gload_lds16(aPtr + (size_t)i * 64 * lda + kOff, As + i * 4096 + ldsseg);
            gload_lds16(bPtr + (size_t)i * 64 * ldb + kOff, Bs + i * 4096 + ldsseg);
        }
        __syncthreads();

        #pragma unroll
        for (int kk = 0; kk < 2; ++kk) {
            bf16x8 af[4], bfr[2];
            #pragma unroll
            for (int m = 0; m < 4; ++m)
                af[m] = *(const bf16x8*)&As[(wr * 64 + m * 16 + l15) * 64 + kk * 32 + lq * 8];
            #pragma unroll
            for (int n = 0; n < 2; ++n)
                bfr[n] = *(const bf16x8*)&Bs[(wc * 32 + n * 16 + l15) * 64 + kk * 32 + lq * 8];
            #pragma unroll
            for (int m = 0; m < 4; ++m)
                #pragma unroll
                for (int n = 0; n < 2; ++n)
                    acc[m][n] = __builtin_amdgcn_mfma_f32_16x16x32_bf16(
                        af[m], bfr[n], acc[m][n], 0, 0, 0);
        }
    }

    #pragma unroll
    for (int m = 0; m < 4; ++m) {
        #pragma unroll
        for (int r = 0; r < 4; ++r) {
            const size_t row = (size_t)(row0 + wr * 64 + m * 16 + lq * 4 + r);
            TOUT* cRow = C + row * ldc + col0 + wc * 32 + l15;
            #pragma unroll
            for (int n = 0; n < 2; ++n)
                store_out(cRow + n * 16, acc[m][n][r]);
        }
    }
}

extern "C" void kernel_launch(void* const* d_in, const int* in_sizes, int n_in,
                              void* d_out, int out_size, void* d_ws, size_t ws_size,
                              hipStream_t stream) {
    const float* hidden_f = (const float*)d_in[0];  // 16384 x 4096 f32
    const float* VT_f     = (const float*)d_in[1];  // 2048 x 4096 f32 (N,K)
    const float* U_f      = (const float*)d_in[2];  // 8 x 512 x 256 f32
    float* out = (float*)d_out;                     // 16384 x 4096 f32

    const long nVT  = 2048L * 4096L;
    const long nU   = 8L * 512L * 256L;
    const long nLat = 16384L * 2048L;

    // lat_b and u_b MUST live in ws (GEMM2 reads them while writing d_out).
    // vt_b may fall back into d_out (read only by GEMM1, which writes ws).
    ushort *vt_b, *u_b, *lat_b;
    const size_t needA = (size_t)(nVT + nU + nLat) * 2;   // ~86 MB
    ushort* w = (ushort*)d_ws;
    lat_b = w;  u_b = lat_b + nLat;
    if (ws_size >= needA) vt_b = u_b + nU;
    else                  vt_b = (ushort*)d_out;          // staged in d_out

    // convert VT + U (~100 MB traffic)
    convert_vt_u_kernel<<<dim3(1024), dim3(256), 0, stream>>>(
        VT_f, vt_b, nVT / 8, U_f, u_b, nU / 8);

    // GEMM1: latent = hidden_f32 * VT^T (fused conversion, 4-wave 128^2)
    // flat grid 2048 = 8 xcd * 16 stripe-rows * 16 col tiles (bxShift=4)
    gemm1_fused_kernel<<<dim3(2048, 1, 1), dim3(256), 0, stream>>>(
        hidden_f, vt_b, lat_b, 4096, 4096, 2048, 4096, 4);

    // GEMM2 (block-diag, 8-wave): out[:, g*512:+512] = latent[:, g*256:+256]*U[g]^T
    gemm_bt8_kernel<float><<<dim3(512, 1, 8), dim3(512), 0, stream>>>(
        lat_b, u_b, out, 2048, 256, 4096, 256, 2,
        256L, 512L * 256L, 512L);
}

// Round 14
// 524.114 us; speedup vs baseline: 1.2007x; 1.0175x over previous
//
#include <hip/hip_runtime.h>
#include <stdint.h>

// HeadwiseLowRankModule: out = blockdiag-GEMM(GEMM(hidden, VT^T), U^T), f32 I/O.
// ROUND 14: r13 + T14 async-STAGE split on GEMM1's fused A-path:
// A f32 loads for tile t+1 are ISSUED right after barrier-2 (fly across the
// MFMA phase); staging phase does only cvt_pk + ds_write from registers.
// GEMM2 8-wave and VT/U convert unchanged from r13 (both passed).

typedef short  bf16x8  __attribute__((ext_vector_type(8)));
typedef float  f32x4   __attribute__((ext_vector_type(4)));
typedef ushort ushort8 __attribute__((ext_vector_type(8)));
typedef float  flt4    __attribute__((ext_vector_type(4)));

__device__ __forceinline__ void gload_lds16(const ushort* g, ushort* l) {
    __builtin_amdgcn_global_load_lds(
        (const __attribute__((address_space(1))) uint32_t*)g,
        (__attribute__((address_space(3))) uint32_t*)l, 16, 0, 0);
}

__device__ __forceinline__ ushort f2bf(float f) {
    union { float f; uint32_t u; } c; c.f = f;
    uint32_t u = c.u;
    uint32_t r = (u + 0x7FFFu + ((u >> 16) & 1u)) >> 16;  // RNE
    return (ushort)r;
}

// packed f32x2 -> bf16x2 (single instruction)
__device__ __forceinline__ uint32_t cvtpk(float lo, float hi) {
    uint32_t r;
    asm("v_cvt_pk_bf16_f32 %0, %1, %2" : "=v"(r) : "v"(lo), "v"(hi));
    return r;
}

// ---- f32 -> bf16 conversion for VT + U only ----
__device__ __forceinline__ void conv_seg(const float* __restrict__ in,
                                         ushort* __restrict__ out,
                                         long n8, int bid, int nblk) {
    const long stride = (long)nblk * 256;
    for (long i = (long)bid * 256 + threadIdx.x; i < n8; i += stride) {
        flt4 a = ((const flt4*)in)[2 * i];
        flt4 b = ((const flt4*)in)[2 * i + 1];
        ushort8 o;
        o[0] = f2bf(a[0]); o[1] = f2bf(a[1]); o[2] = f2bf(a[2]); o[3] = f2bf(a[3]);
        o[4] = f2bf(b[0]); o[5] = f2bf(b[1]); o[6] = f2bf(b[2]); o[7] = f2bf(b[3]);
        ((ushort8*)out)[i] = o;
    }
}

__global__ __launch_bounds__(256) void convert_vt_u_kernel(
    const float* __restrict__ vt_f, ushort* __restrict__ vt_b, long nVT8,
    const float* __restrict__ u_f,  ushort* __restrict__ u_b,  long nU8)
{
    const int b = blockIdx.x;
    if (b < 896) conv_seg(vt_f, vt_b, nVT8, b,       896);
    else         conv_seg(u_f,  u_b,  nU8,  b - 896, 128);
}

// ---- store helpers ----
__device__ __forceinline__ void store_out(ushort* p, float v) { *p = f2bf(v); }
__device__ __forceinline__ void store_out(float*  p, float v) { *p = v; }

// =====================================================================
// GEMM1: latent[16384 x 2048] = hidden_f32[16384 x 4096] * VT_bf16^T
// 4-wave 128x128 body; A staged from f32 with T14 split:
//   loads(t+1) issued after barrier-2  ->  fly across MFMA phase
//   staging phase: cvt_pk + ds_write only (no load wait)
// =====================================================================
__global__ __launch_bounds__(256) void gemm1_fused_kernel(
    const float* __restrict__ Af,
    const ushort* __restrict__ B,
    ushort* __restrict__ C,
    int lda, int ldb, int ldc, int K, int bxShift)
{
    __shared__ ushort As[128 * 64];   // 16 KiB
    __shared__ ushort Bs[128 * 64];   // 16 KiB

    const int tid  = threadIdx.x;
    const int lane = tid & 63;
    const int wave = tid >> 6;

    // XCD-aware swizzle (bijective; grid = 8*16*2^bxShift)
    const int bid = blockIdx.x;
    const int xcd = bid & 7;
    const int rr  = bid >> 3;
    const int by  = xcd * 16 + (rr >> bxShift);
    const int bx  = rr & ((1 << bxShift) - 1);

    const int row0 = by * 128;
    const int col0 = bx * 128;

    const int wr = wave >> 1;
    const int wc = wave & 1;

    const int l15    = lane & 15;
    const int lq     = lane >> 4;    // 0..3
    const int lrow   = lane >> 3;    // 0..7
    const int lchunk = lane & 7;     // 0..7

    f32x4 acc[4][4] = {};
    flt4 pa[8];                      // t+1 A data in flight (32 VGPR)

    const float*  aF   = Af + (size_t)(row0 + wave * 32 + lrow) * lda + lchunk * 8;
    const ushort* bPtr = B  + (size_t)(col0 + wave * 32 + lrow) * ldb + lchunk * 8;
    ushort* aDstBase = As + wave * 4 * 512 + lane * 8;  // per-thread LDS slot

    const int nkt = K / 64;

    // prologue: load tile 0's A into registers
    #pragma unroll
    for (int i = 0; i < 4; ++i) {
        const float* src = aF + (size_t)(i * 8) * lda;
        pa[2 * i]     = *(const flt4*)(src);
        pa[2 * i + 1] = *(const flt4*)(src + 4);
    }

    for (int kt = 0; kt < nkt; ++kt) {
        const int kOff = kt * 64;
        __syncthreads();   // b1: prev compute done; pa loads drained (overlapped)
        // B: async global->LDS (4 x 16B)
        #pragma unroll
        for (int i = 0; i < 4; ++i)
            gload_lds16(bPtr + (size_t)i * 8 * ldb + kOff, Bs + (wave * 4 + i) * 512);
        // A: cvt_pk + ds_write from registers (no load latency here)
        #pragma unroll
        for (int i = 0; i < 4; ++i) {
            uint4 w;
            w.x = cvtpk(pa[2*i][0],   pa[2*i][1]);
            w.y = cvtpk(pa[2*i][2],   pa[2*i][3]);
            w.z = cvtpk(pa[2*i+1][0], pa[2*i+1][1]);
            w.w = cvtpk(pa[2*i+1][2], pa[2*i+1][3]);
            *(uint4*)(aDstBase + i * 512) = w;
        }
        __syncthreads();   // b2: drains B gload_lds + A ds_writes

        // T14: issue next tile's A loads NOW -- they fly across the MFMAs
        if (kt + 1 < nkt) {
            const int kN = kOff + 64;
            #pragma unroll
            for (int i = 0; i < 4; ++i) {
                const float* src = aF + (size_t)(i * 8) * lda + kN;
                pa[2 * i]     = *(const flt4*)(src);
                pa[2 * i + 1] = *(const flt4*)(src + 4);
            }
        }

        #pragma unroll
        for (int kk = 0; kk < 2; ++kk) {
            bf16x8 af[4], bfr[4];
            #pragma unroll
            for (int m = 0; m < 4; ++m)
                af[m] = *(const bf16x8*)&As[(wr * 64 + m * 16 + l15) * 64 + kk * 32 + lq * 8];
            #pragma unroll
            for (int n = 0; n < 4; ++n)
                bfr[n] = *(const bf16x8*)&Bs[(wc * 64 + n * 16 + l15) * 64 + kk * 32 + lq * 8];
            #pragma unroll
            for (int m = 0; m < 4; ++m)
                #pragma unroll
                for (int n = 0; n < 4; ++n)
                    acc[m][n] = __builtin_amdgcn_mfma_f32_16x16x32_bf16(
                        af[m], bfr[n], acc[m][n], 0, 0, 0);
        }
    }

    // C/D layout: col = lane&15, row = (lane>>4)*4 + reg
    #pragma unroll
    for (int m = 0; m < 4; ++m) {
        #pragma unroll
        for (int r = 0; r < 4; ++r) {
            const size_t row = (size_t)(row0 + wr * 64 + m * 16 + lq * 4 + r);
            ushort* cRow = C + row * ldc + col0 + wc * 64 + l15;
            #pragma unroll
            for (int n = 0; n < 4; ++n)
                cRow[n * 16] = f2bf(acc[m][n][r]);
        }
    }
}

// =====================================================================
// GEMM2 (8-wave, r12/r13 verbatim): block-diagonal
// out[:, g*512:+512] = latent[:, g*256:+256] * U[g]^T, f32 out.
// =====================================================================
template <typename TOUT>
__global__ __launch_bounds__(512) void gemm_bt8_kernel(
    const ushort* __restrict__ A,
    const ushort* __restrict__ B,
    TOUT* __restrict__ C,
    int lda, int ldb, int ldc, int K, int bxShift,
    long aOffZ, long bOffZ, long cOffZ)
{
    A += (size_t)blockIdx.z * aOffZ;
    B += (size_t)blockIdx.z * bOffZ;
    C += (size_t)blockIdx.z * cOffZ;

    __shared__ ushort As[128 * 64];
    __shared__ ushort Bs[128 * 64];

    const int tid  = threadIdx.x;
    const int lane = tid & 63;
    const int wave = tid >> 6;       // 0..7

    const int bid = blockIdx.x;
    const int xcd = bid & 7;
    const int rr  = bid >> 3;
    const int by  = xcd * 16 + (rr >> bxShift);
    const int bx  = rr & ((1 << bxShift) - 1);

    const int row0 = by * 128;
    const int col0 = bx * 128;

    const int wr = wave >> 2;        // 0..1
    const int wc = wave & 3;         // 0..3

    const int l15    = lane & 15;
    const int lq     = lane >> 4;
    const int lrow   = lane >> 3;
    const int lchunk = lane & 7;

    f32x4 acc[4][2] = {};

    const ushort* aPtr = A + (size_t)(row0 + wave * 8 + lrow) * lda + lchunk * 8;
    const ushort* bPtr = B + (size_t)(col0 + wave * 8 + lrow) * ldb + lchunk * 8;
    const int ldsseg = wave * 512;

    const int nkt = K / 64;
    for (int kt = 0; kt < nkt; ++kt) {
        const int kOff = kt * 64;
        __syncthreads();
        #pragma unroll
        for (int i = 0; i < 2; ++i) {
            gload_lds16(aPtr + (size_t)i * 64 * lda + kOff, As + i * 4096 + ldsseg);
            gload_lds16(bPtr + (size_t)i * 64 * ldb + kOff, Bs + i * 4096 + ldsseg);
        }
        __syncthreads();

        #pragma unroll
        for (int kk = 0; kk < 2; ++kk) {
            bf16x8 af[4], bfr[2];
            #pragma unroll
            for (int m = 0; m < 4; ++m)
                af[m] = *(const bf16x8*)&As[(wr * 64 + m * 16 + l15) * 64 + kk * 32 + lq * 8];
            #pragma unroll
            for (int n = 0; n < 2; ++n)
                bfr[n] = *(const bf16x8*)&Bs[(wc * 32 + n * 16 + l15) * 64 + kk * 32 + lq * 8];
            #pragma unroll
            for (int m = 0; m < 4; ++m)
                #pragma unroll
                for (int n = 0; n < 2; ++n)
                    acc[m][n] = __builtin_amdgcn_mfma_f32_16x16x32_bf16(
                        af[m], bfr[n], acc[m][n], 0, 0, 0);
        }
    }

    #pragma unroll
    for (int m = 0; m < 4; ++m) {
        #pragma unroll
        for (int r = 0; r < 4; ++r) {
            const size_t row = (size_t)(row0 + wr * 64 + m * 16 + lq * 4 + r);
            TOUT* cRow = C + row * ldc + col0 + wc * 32 + l15;
            #pragma unroll
            for (int n = 0; n < 2; ++n)
                store_out(cRow + n * 16, acc[m][n][r]);
        }
    }
}

extern "C" void kernel_launch(void* const* d_in, const int* in_sizes, int n_in,
                              void* d_out, int out_size, void* d_ws, size_t ws_size,
                              hipStream_t stream) {
    const float* hidden_f = (const float*)d_in[0];  // 16384 x 4096 f32
    const float* VT_f     = (const float*)d_in[1];  // 2048 x 4096 f32 (N,K)
    const float* U_f      = (const float*)d_in[2];  // 8 x 512 x 256 f32
    float* out = (float*)d_out;                     // 16384 x 4096 f32

    const long nVT  = 2048L * 4096L;
    const long nU   = 8L * 512L * 256L;
    const long nLat = 16384L * 2048L;

    // lat_b and u_b MUST live in ws (GEMM2 reads them while writing d_out).
    // vt_b may fall back into d_out (read only by GEMM1, which writes ws).
    ushort *vt_b, *u_b, *lat_b;
    const size_t needA = (size_t)(nVT + nU + nLat) * 2;   // ~86 MB
    ushort* w = (ushort*)d_ws;
    lat_b = w;  u_b = lat_b + nLat;
    if (ws_size >= needA) vt_b = u_b + nU;
    else                  vt_b = (ushort*)d_out;          // staged in d_out

    // convert VT + U (~100 MB traffic)
    convert_vt_u_kernel<<<dim3(1024), dim3(256), 0, stream>>>(
        VT_f, vt_b, nVT / 8, U_f, u_b, nU / 8);

    // GEMM1: latent = hidden_f32 * VT^T (fused conversion + T14 prefetch)
    gemm1_fused_kernel<<<dim3(2048, 1, 1), dim3(256), 0, stream>>>(
        hidden_f, vt_b, lat_b, 4096, 4096, 2048, 4096, 4);

    // GEMM2 (block-diag, 8-wave): out[:, g*512:+512] = latent[:, g*256:+256]*U[g]^T
    gemm_bt8_kernel<float><<<dim3(512, 1, 8), dim3(512), 0, stream>>>(
        lat_b, u_b, out, 2048, 256, 4096, 256, 2,
        256L, 512L * 256L, 512L);
}